// Round 15
// baseline (156.676 us; speedup 1.0000x reference)
//
#include <hip/hip_runtime.h>
#include <hip/hip_bf16.h>

// GraphSAGE 2-layer, N=100000, E=1200000, D: 64 -> 64 -> 32, fp32 in/out.
// R15: layer-2 algebraic restructure: mean(h)@W2_l == mean(h@W2_l).
//  - y2 = h@W2_l fused into dense1's epilogue (h already transposed in the
//    LDS 'to' tile) -> 32-wide y2 rows.
//  - gather2 gathers y2: HALF the bytes (64B rows), 16 rows per 1KB load
//    (16 slots x 4 quads) -> most nodes finish in one batch.
//  - dense2 slims: stage only h, half FMAs, add meanY2 in epilogue.
// R14 build kept: atomic-free 256-queue compact + LDS CSR (pad to 16 now).
// Established (R6/R10-R12): per-edge device atomics cost ~32-40B memory-side
// traffic each -> build uses LDS atomics + per-block reservations only.

#define D1 64
#define NQ 256               // sub-partition queues (== blockDim for compact)
#define SUBN 391             // ceil(N/256); d/SUBN <= 255 for d < 100096
#define QCAP 5632            // per-queue cap; avg 4687, sigma ~68 (13+ sigma)
#define LCAP 11520           // staging cap >= QCAP + SUBN*15 = 11497
#define BE 5120              // edges per phase-A block (2 streaming passes)

static __device__ __forceinline__ float bf2f(ushort u) {
    unsigned int x = ((unsigned int)u) << 16;
    return __uint_as_float(x);
}
static __device__ __forceinline__ ushort f2bf(float f) {
    union { __hip_bfloat16 b; ushort u; } cv;
    cv.b = __float2bfloat16(f);   // RNE
    return cv.u;
}
static __device__ __forceinline__ float lo2f(unsigned u) {
    return __uint_as_float(u << 16);
}
static __device__ __forceinline__ float hi2f(unsigned u) {
    return __uint_as_float(u & 0xffff0000u);
}
static __device__ __forceinline__ unsigned packbf(float x, float y) {
    return (unsigned)f2bf(x) | ((unsigned)f2bf(y) << 16);
}

// ---- phase A: compact edges into 256 sub-partition queues ----------------

__global__ __launch_bounds__(256)
void compact_edges256(const int* __restrict__ src, const int* __restrict__ dst,
                      int* __restrict__ tail, int2* __restrict__ queue, int E) {
    __shared__ int hist[NQ];
    __shared__ int base[NQ];
    int tid = threadIdx.x;
    int e0 = blockIdx.x * BE;
    int e1 = min(E, e0 + BE);

    hist[tid] = 0;
    __syncthreads();
    for (int e = e0 + tid; e < e1; e += 256)
        atomicAdd(&hist[dst[e] / SUBN], 1);          // LDS atomic
    __syncthreads();
    base[tid] = atomicAdd(&tail[tid], hist[tid]);    // 256 global atomics/blk
    hist[tid] = 0;                                   // reuse as cursor
    __syncthreads();
    for (int e = e0 + tid; e < e1; e += 256) {
        int d = dst[e];
        int s = src[e];
        int p = d / SUBN;
        int pos = base[p] + atomicAdd(&hist[p], 1);  // LDS atomic
        if (pos < QCAP) queue[(size_t)p * QCAP + pos] = make_int2(s, d);
    }
}

// ---- phase B: per-sub-partition exact CSR built entirely in LDS ---------
// Lists padded to multiple of 16 with sentinel N (zero feature row).

__global__ __launch_bounds__(256)
void csr_build_local(const int2* __restrict__ queue, const int* __restrict__ tail,
                     int2* __restrict__ info, int* __restrict__ nbr, int N) {
    __shared__ int lcnt[512];            // >= SUBN
    __shared__ int psum[256];
    __shared__ int lnbr[LCAP];           // 46 KB staging
    int tid = threadIdx.x;
    int p = blockIdx.x;
    int lo = p * SUBN;
    int nt = min(tail[p], QCAP);
    const int2* q = queue + (size_t)p * QCAP;
    int gbase = p * LCAP;

    lcnt[tid] = 0; lcnt[tid + 256] = 0;
    __syncthreads();
    for (int e = tid; e < nt; e += 256)
        atomicAdd(&lcnt[q[e].y - lo], 1);            // LDS atomic
    __syncthreads();

    // exclusive scan over PADDED sizes; thread owns elements 2t, 2t+1
    int d0 = lcnt[2 * tid], d1 = lcnt[2 * tid + 1];
    int p0 = (d0 + 15) & ~15, p1 = (d1 + 15) & ~15;
    int s = p0 + p1;
    psum[tid] = s;
    __syncthreads();
    for (int off = 1; off < 256; off <<= 1) {
        int a = (tid >= off) ? psum[tid - off] : 0;
        __syncthreads();
        psum[tid] += a;
        __syncthreads();
    }
    int st0 = psum[tid] - s;
    int st1 = st0 + p0;
    int ptot = psum[255];

    {
        int li = 2 * tid, n = lo + li;
        if (li < SUBN && n < N) info[n] = make_int2(gbase + st0, d0);
        lcnt[li] = st0;                  // local cursor
        li = 2 * tid + 1; n = lo + li;
        if (li < SUBN && n < N) info[n] = make_int2(gbase + st1, d1);
        lcnt[li] = st1;
    }
    __syncthreads();

    for (int e = tid; e < nt; e += 256) {
        int2 pr = q[e];
        int pos = atomicAdd(&lcnt[pr.y - lo], 1);    // LDS atomic
        lnbr[pos] = pr.x;
    }
    __syncthreads();

    // fill pad slots with sentinel N
    for (int j = st0 + d0; j < st0 + p0; ++j) lnbr[j] = N;
    for (int j = st1 + d1; j < st1 + p1; ++j) lnbr[j] = N;
    __syncthreads();

    for (int i = tid; i < ptot; i += 256)            // coalesced copy-out
        nbr[gbase + i] = lnbr[i];
}

// ---- fp32 -> bf16 convert + pipeline init (tail zero, sentinel rows) ----

__global__ __launch_bounds__(256)
void cvt_bf16_init(const float* __restrict__ in, ushort* __restrict__ xh,
                   ushort* __restrict__ y2, int* __restrict__ tail,
                   int n4, int N) {
    int i = blockIdx.x * 256 + threadIdx.x;   // one float4 -> ushort4
    if (i < n4) {
        float4 v = *(const float4*)&in[(size_t)i * 4];
        ushort4 u;
        u.x = f2bf(v.x); u.y = f2bf(v.y); u.z = f2bf(v.z); u.w = f2bf(v.w);
        *(ushort4*)&xh[(size_t)i * 4] = u;
    }
    if (blockIdx.x == 0) tail[threadIdx.x] = 0;               // NQ == 256
    if (blockIdx.x == 1) {                                    // zero rows N
        if (threadIdx.x < D1) xh[(size_t)N * D1 + threadIdx.x] = 0;
        if (threadIdx.x < 32) y2[(size_t)N * 32 + threadIdx.x] = 0;
    }
}

// ---- gather L1: mean of 64-wide bf16 rows. Wave per node. ----------------
// Slots (r,c)=(lane>>3, lane&7): 8 rows per 1KB instruction, unroll x2.

#define ACC8(u) do { \
    a0 += lo2f((u).x); a1 += hi2f((u).x); \
    a2 += lo2f((u).y); a3 += hi2f((u).y); \
    a4 += lo2f((u).z); a5 += hi2f((u).z); \
    a6 += lo2f((u).w); a7 += hi2f((u).w); } while (0)

__global__ __launch_bounds__(256)
void gather_mean8(const ushort* __restrict__ feat,
                  const int2* __restrict__ info,
                  const int* __restrict__ nbr,
                  ushort* __restrict__ mean, int N) {
    int wid  = (blockIdx.x * 256 + threadIdx.x) >> 6;
    int lane = threadIdx.x & 63;
    if (wid >= N) return;
    int2 ii = info[wid];
    int deg = ii.y;
    int m8 = (deg + 7) & ~7;
    const int* nb = nbr + ii.x;
    int r = lane >> 3;          // neighbor slot 0..7
    int c = lane & 7;           // uint4 quad within 64-feature row
    const uint4* f4 = (const uint4*)feat;

    float a0 = 0, a1 = 0, a2 = 0, a3 = 0, a4 = 0, a5 = 0, a6 = 0, a7 = 0;
    int i = 0;
    for (; i + 16 <= m8; i += 16) {
        int e0 = nb[i + r];
        int e1 = nb[i + 8 + r];
        uint4 u0 = f4[(size_t)e0 * 8 + c];
        uint4 u1 = f4[(size_t)e1 * 8 + c];
        ACC8(u0);
        ACC8(u1);
    }
    if (i < m8) {
        int e0 = nb[i + r];
        uint4 u0 = f4[(size_t)e0 * 8 + c];
        ACC8(u0);
    }

    a0 += __shfl_xor(a0, 8, 64); a0 += __shfl_xor(a0, 16, 64); a0 += __shfl_xor(a0, 32, 64);
    a1 += __shfl_xor(a1, 8, 64); a1 += __shfl_xor(a1, 16, 64); a1 += __shfl_xor(a1, 32, 64);
    a2 += __shfl_xor(a2, 8, 64); a2 += __shfl_xor(a2, 16, 64); a2 += __shfl_xor(a2, 32, 64);
    a3 += __shfl_xor(a3, 8, 64); a3 += __shfl_xor(a3, 16, 64); a3 += __shfl_xor(a3, 32, 64);
    a4 += __shfl_xor(a4, 8, 64); a4 += __shfl_xor(a4, 16, 64); a4 += __shfl_xor(a4, 32, 64);
    a5 += __shfl_xor(a5, 8, 64); a5 += __shfl_xor(a5, 16, 64); a5 += __shfl_xor(a5, 32, 64);
    a6 += __shfl_xor(a6, 8, 64); a6 += __shfl_xor(a6, 16, 64); a6 += __shfl_xor(a6, 32, 64);
    a7 += __shfl_xor(a7, 8, 64); a7 += __shfl_xor(a7, 16, 64); a7 += __shfl_xor(a7, 32, 64);

    if (r == 0) {               // lanes 0..7 write the 128B mean row
        float inv = 1.0f / fmaxf((float)deg, 1.0f);
        uint4 o;
        o.x = packbf(a0 * inv, a1 * inv);
        o.y = packbf(a2 * inv, a3 * inv);
        o.z = packbf(a4 * inv, a5 * inv);
        o.w = packbf(a6 * inv, a7 * inv);
        ((uint4*)mean)[(size_t)wid * 8 + c] = o;
    }
}

// ---- gather L2: mean of 32-wide y2 rows. Wave per node. ------------------
// Slots (r,c)=(lane>>2, lane&3): 16 rows per 1KB instruction.

__global__ __launch_bounds__(256)
void gather_mean16(const ushort* __restrict__ feat,   // y2 [N+1][32] bf16
                   const int2* __restrict__ info,
                   const int* __restrict__ nbr,
                   ushort* __restrict__ mean, int N) {
    int wid  = (blockIdx.x * 256 + threadIdx.x) >> 6;
    int lane = threadIdx.x & 63;
    if (wid >= N) return;
    int2 ii = info[wid];
    int deg = ii.y;
    int m16 = (deg + 15) & ~15;
    const int* nb = nbr + ii.x;
    int r = lane >> 2;          // neighbor slot 0..15
    int c = lane & 3;           // uint4 quad within 32-feature row
    const uint4* f4 = (const uint4*)feat;

    float a0 = 0, a1 = 0, a2 = 0, a3 = 0, a4 = 0, a5 = 0, a6 = 0, a7 = 0;
    int i = 0;
    for (; i + 32 <= m16; i += 32) {
        int e0 = nb[i + r];
        int e1 = nb[i + 16 + r];
        uint4 u0 = f4[(size_t)e0 * 4 + c];
        uint4 u1 = f4[(size_t)e1 * 4 + c];
        ACC8(u0);
        ACC8(u1);
    }
    if (i < m16) {
        int e0 = nb[i + r];
        uint4 u0 = f4[(size_t)e0 * 4 + c];
        ACC8(u0);
    }

    // reduce across 16 slots (lane bits 2..5)
    a0 += __shfl_xor(a0, 4, 64); a0 += __shfl_xor(a0, 8, 64); a0 += __shfl_xor(a0, 16, 64); a0 += __shfl_xor(a0, 32, 64);
    a1 += __shfl_xor(a1, 4, 64); a1 += __shfl_xor(a1, 8, 64); a1 += __shfl_xor(a1, 16, 64); a1 += __shfl_xor(a1, 32, 64);
    a2 += __shfl_xor(a2, 4, 64); a2 += __shfl_xor(a2, 8, 64); a2 += __shfl_xor(a2, 16, 64); a2 += __shfl_xor(a2, 32, 64);
    a3 += __shfl_xor(a3, 4, 64); a3 += __shfl_xor(a3, 8, 64); a3 += __shfl_xor(a3, 16, 64); a3 += __shfl_xor(a3, 32, 64);
    a4 += __shfl_xor(a4, 4, 64); a4 += __shfl_xor(a4, 8, 64); a4 += __shfl_xor(a4, 16, 64); a4 += __shfl_xor(a4, 32, 64);
    a5 += __shfl_xor(a5, 4, 64); a5 += __shfl_xor(a5, 8, 64); a5 += __shfl_xor(a5, 16, 64); a5 += __shfl_xor(a5, 32, 64);
    a6 += __shfl_xor(a6, 4, 64); a6 += __shfl_xor(a6, 8, 64); a6 += __shfl_xor(a6, 16, 64); a6 += __shfl_xor(a6, 32, 64);
    a7 += __shfl_xor(a7, 4, 64); a7 += __shfl_xor(a7, 8, 64); a7 += __shfl_xor(a7, 16, 64); a7 += __shfl_xor(a7, 32, 64);

    if (r == 0) {               // lanes 0..3 write the 64B mean row
        float inv = 1.0f / fmaxf((float)deg, 1.0f);
        uint4 o;
        o.x = packbf(a0 * inv, a1 * inv);
        o.y = packbf(a2 * inv, a3 * inv);
        o.z = packbf(a4 * inv, a5 * inv);
        o.w = packbf(a6 * inv, a7 * inv);
        ((uint4*)mean)[(size_t)wid * 4 + c] = o;
    }
}

// ---- dense1: h = relu(mean1@W1l + b1 + x@W1r); also y2 = h@W2l -----------
// Block = 64 nodes; lane = node; wave w owns j-slice [w*16,(w+1)*16).
// h is transposed in the LDS 'to' tile -> y2 GEMM reads it for free.

#define TA_STRIDE 66

__global__ __launch_bounds__(256)
void dense_sage1(const ushort* __restrict__ Am,    // mean1 [N][64] bf16
                 const ushort* __restrict__ Ax,    // xh [N][64] bf16
                 const float* __restrict__ Wm,     // W1l [64][64]
                 const float* __restrict__ Wx,     // W1r [64][64]
                 const float* __restrict__ bias,   // b1 [64]
                 const float* __restrict__ W2l,    // [64][32]
                 ushort* __restrict__ hh,          // [N+..][64] bf16
                 ushort* __restrict__ y2,          // [N+1][32] bf16
                 int N) {
    __shared__ char smraw[128 * TA_STRIDE * 2];   // 16.9 KB
    ushort* ta = (ushort*)smraw;
    float*  to = (float*)smraw;

    int tid  = threadIdx.x;
    int w    = tid >> 6;
    int lane = tid & 63;
    int n0 = blockIdx.x * 64;

    #pragma unroll
    for (int i = 0; i < 8; ++i) {
        int flat = i * 256 + tid;
        int row  = flat >> 4;
        int c4   = (flat & 15) * 4;
        const ushort* A = (row < 64) ? Am : Ax;
        int node = row & 63;
        int grow = n0 + node;
        ushort4 u = make_ushort4(0, 0, 0, 0);
        if (grow < N) u = *(const ushort4*)&A[(size_t)grow * D1 + c4];
        int kb = ((row < 64) ? 0 : 64) + c4;
        ta[(kb + 0) * TA_STRIDE + node] = u.x;
        ta[(kb + 1) * TA_STRIDE + node] = u.y;
        ta[(kb + 2) * TA_STRIDE + node] = u.z;
        ta[(kb + 3) * TA_STRIDE + node] = u.w;
    }
    __syncthreads();

    int jb = __builtin_amdgcn_readfirstlane(w * 16);
    float c[16];
    #pragma unroll
    for (int j = 0; j < 16; ++j) c[j] = bias[jb + j];

    #pragma unroll 4
    for (int k = 0; k < 64; ++k) {
        float a = bf2f(ta[k * TA_STRIDE + lane]);
        #pragma unroll
        for (int j = 0; j < 16; ++j)
            c[j] = fmaf(a, Wm[k * 64 + jb + j], c[j]);
    }
    #pragma unroll 4
    for (int k = 0; k < 64; ++k) {
        float a = bf2f(ta[(64 + k) * TA_STRIDE + lane]);
        #pragma unroll
        for (int j = 0; j < 16; ++j)
            c[j] = fmaf(a, Wx[k * 64 + jb + j], c[j]);
    }
    #pragma unroll
    for (int j = 0; j < 16; ++j) c[j] = fmaxf(c[j], 0.0f);   // relu

    __syncthreads();   // A-tile consumed -> reuse LDS as fp32 h tile
    #pragma unroll
    for (int j = 0; j < 16; ++j) to[(jb + j) * 65 + lane] = c[j];
    __syncthreads();

    // coalesced hh store (reads 'to')
    #pragma unroll
    for (int i = 0; i < 4; ++i) {
        int flat = i * 256 + tid;
        int node = flat >> 4;
        int q    = flat & 15;
        int grow = n0 + node;
        if (grow < N) {
            ushort4 u;
            u.x = f2bf(to[(q * 4 + 0) * 65 + node]);
            u.y = f2bf(to[(q * 4 + 1) * 65 + node]);
            u.z = f2bf(to[(q * 4 + 2) * 65 + node]);
            u.w = f2bf(to[(q * 4 + 3) * 65 + node]);
            *(ushort4*)&hh[(size_t)grow * D1 + q * 4] = u;
        }
    }

    // y2 = h @ W2l (reads 'to'); wave w owns jj-slice [w*8,(w+1)*8)
    int jb2 = __builtin_amdgcn_readfirstlane(w * 8);
    float c2[8];
    #pragma unroll
    for (int j = 0; j < 8; ++j) c2[j] = 0.0f;
    #pragma unroll 4
    for (int k = 0; k < 64; ++k) {
        float a = to[k * 65 + lane];
        #pragma unroll
        for (int j = 0; j < 8; ++j)
            c2[j] = fmaf(a, W2l[k * 32 + jb2 + j], c2[j]);
    }
    __syncthreads();   // all 'to' reads done -> reuse as y2 tile
    #pragma unroll
    for (int j = 0; j < 8; ++j) to[(jb2 + j) * 65 + lane] = c2[j];
    __syncthreads();

    #pragma unroll
    for (int i = 0; i < 2; ++i) {
        int flat = i * 256 + tid;
        int node = flat >> 3;
        int q    = flat & 7;
        int grow = n0 + node;
        if (grow < N) {
            ushort4 u;
            u.x = f2bf(to[(q * 4 + 0) * 65 + node]);
            u.y = f2bf(to[(q * 4 + 1) * 65 + node]);
            u.z = f2bf(to[(q * 4 + 2) * 65 + node]);
            u.w = f2bf(to[(q * 4 + 3) * 65 + node]);
            *(ushort4*)&y2[(size_t)grow * 32 + q * 4] = u;
        }
    }
}

// ---- dense2: out = meanY2 + h@W2r + b2 (fp32 out) ------------------------
// Stage only h (64 rows); meanY2 added coalesced in the epilogue.

__global__ __launch_bounds__(256)
void dense_sage2(const ushort* __restrict__ Ax,     // hh [N][64] bf16
                 const ushort* __restrict__ mY2,    // meanY2 [N][32] bf16
                 const float* __restrict__ Wx,      // W2r [64][32]
                 const float* __restrict__ bias,    // b2 [32]
                 float* __restrict__ outp, int N) {
    __shared__ char smraw[64 * TA_STRIDE * 2 + 32 * 65 * 4];  // 16.8 KB
    ushort* ta = (ushort*)smraw;
    float*  to = (float*)(smraw + 64 * TA_STRIDE * 2);

    int tid  = threadIdx.x;
    int w    = tid >> 6;
    int lane = tid & 63;
    int n0 = blockIdx.x * 64;

    #pragma unroll
    for (int i = 0; i < 4; ++i) {
        int flat = i * 256 + tid;
        int row  = flat >> 4;            // node 0..63
        int c4   = (flat & 15) * 4;
        int grow = n0 + row;
        ushort4 u = make_ushort4(0, 0, 0, 0);
        if (grow < N) u = *(const ushort4*)&Ax[(size_t)grow * D1 + c4];
        ta[(c4 + 0) * TA_STRIDE + row] = u.x;
        ta[(c4 + 1) * TA_STRIDE + row] = u.y;
        ta[(c4 + 2) * TA_STRIDE + row] = u.z;
        ta[(c4 + 3) * TA_STRIDE + row] = u.w;
    }
    __syncthreads();

    int jb = __builtin_amdgcn_readfirstlane(w * 8);
    float c[8];
    #pragma unroll
    for (int j = 0; j < 8; ++j) c[j] = bias[jb + j];

    #pragma unroll 4
    for (int k = 0; k < 64; ++k) {
        float a = bf2f(ta[k * TA_STRIDE + lane]);
        #pragma unroll
        for (int j = 0; j < 8; ++j)
            c[j] = fmaf(a, Wx[k * 32 + jb + j], c[j]);
    }

    #pragma unroll
    for (int j = 0; j < 8; ++j) to[(jb + j) * 65 + lane] = c[j];
    __syncthreads();

    #pragma unroll
    for (int i = 0; i < 2; ++i) {
        int flat = i * 256 + tid;
        int node = flat >> 3;
        int q    = flat & 7;
        int grow = n0 + node;
        if (grow < N) {
            ushort4 m = *(const ushort4*)&mY2[(size_t)grow * 32 + q * 4];
            float4 v;
            v.x = to[(q * 4 + 0) * 65 + node] + bf2f(m.x);
            v.y = to[(q * 4 + 1) * 65 + node] + bf2f(m.y);
            v.z = to[(q * 4 + 2) * 65 + node] + bf2f(m.z);
            v.w = to[(q * 4 + 3) * 65 + node] + bf2f(m.w);
            *(float4*)&outp[(size_t)grow * 32 + q * 4] = v;
        }
    }
}

// ---- launch -------------------------------------------------------------

extern "C" void kernel_launch(void* const* d_in, const int* in_sizes, int n_in,
                              void* d_out, int out_size, void* d_ws, size_t ws_size,
                              hipStream_t stream) {
    const float* x   = (const float*)d_in[0];
    const int*   ei  = (const int*)d_in[1];
    const float* W1l = (const float*)d_in[2];
    const float* W1r = (const float*)d_in[3];
    const float* b1  = (const float*)d_in[4];
    const float* W2l = (const float*)d_in[5];
    const float* W2r = (const float*)d_in[6];
    const float* b2  = (const float*)d_in[7];
    float* out = (float*)d_out;

    int N = in_sizes[0] / D1;
    int E = in_sizes[1] / 2;
    const int* src = ei;
    const int* dst = ei + E;

    char* ws = (char*)d_ws;
    auto alignup = [](size_t v) { return (v + 255) & ~(size_t)255; };
    size_t off = 0;
    int*    tail  = (int*)(ws + off);    off += alignup(NQ * 4);
    int2*   queue = (int2*)(ws + off);   off += alignup((size_t)NQ * QCAP * 8);
    int*    nbr   = (int*)(ws + off);    off += alignup((size_t)NQ * LCAP * 4);
    int2*   info  = (int2*)(ws + off);   off += alignup((size_t)N * 8);
    ushort* xh    = (ushort*)(ws + off); off += alignup((size_t)(N + 1) * D1 * 2);
    ushort* hh    = (ushort*)(ws + off); off += alignup((size_t)(N + 1) * D1 * 2);
    ushort* y2    = (ushort*)(ws + off); off += alignup((size_t)(N + 1) * 32 * 2);
    // layer-1 mean lives in d_out (fully overwritten by dense2 at the end);
    // meanY2 reuses xh rows (dead after dense1).
    ushort* mean1  = (ushort*)d_out;     // N*64*2B = 12.8MB == out_size bytes
    ushort* meanY2 = xh;

    int gb = (N + 3) / 4;         // gather: wave per node, 4 waves/block
    int db = (N + 63) / 64;       // dense: 64 nodes/block
    int cb = ((N * D1 / 4) + 255) / 256;
    int ab = (E + BE - 1) / BE;   // phase-A blocks (235)

    cvt_bf16_init<<<cb, 256, 0, stream>>>(x, xh, y2, tail, N * D1 / 4, N);
    compact_edges256<<<ab, 256, 0, stream>>>(src, dst, tail, queue, E);
    csr_build_local<<<NQ, 256, 0, stream>>>(queue, tail, info, nbr, N);

    gather_mean8<<<gb, 256, 0, stream>>>(xh, info, nbr, mean1, N);
    dense_sage1<<<db, 256, 0, stream>>>(mean1, xh, W1l, W1r, b1, W2l, hh, y2, N);
    gather_mean16<<<gb, 256, 0, stream>>>(y2, info, nbr, meanY2, N);
    dense_sage2<<<db, 256, 0, stream>>>(hh, meanY2, W2r, b2, out, N);
}

// Round 16
// 156.671 us; speedup vs baseline: 1.0000x; 1.0000x over previous
//
#include <hip/hip_runtime.h>
#include <hip/hip_bf16.h>

// GraphSAGE 2-layer, N=100000, E=1200000, D: 64 -> 64 -> 32, fp32 in/out.
// R16: full layer-2 push-through. mean(h)@W2l == mean(h@W2l), so dense1's
// epilogue computes BOTH y2l=h@W2l (bf16, gathered) and y2r=h@W2r (fp32,
// per-node) from the LDS-resident h tile (shared ds_reads, 16 FMA/read).
// out[n] = mean(y2l[nbrs]) + y2r[n] + b2 is fused into gather2's epilogue.
// Deletes: dense2 kernel, hh buffer (h never hits HBM), one dispatch.
// Build: atomic-free 256-queue compact + LDS CSR, pad-16 (R14).
// Established (R6/R10-R12): per-edge device atomics cost ~32-40B memory-side
// traffic each -> build uses LDS atomics + per-block reservations only.

#define D1 64
#define NQ 256               // sub-partition queues (== blockDim for compact)
#define SUBN 391             // ceil(N/256); d/SUBN <= 255 for d < 100096
#define QCAP 5632            // per-queue cap; avg 4687, sigma ~68 (13+ sigma)
#define LCAP 11520           // staging cap >= QCAP + SUBN*15 = 11497
#define BE 5120              // edges per phase-A block (2 streaming passes)

static __device__ __forceinline__ float bf2f(ushort u) {
    unsigned int x = ((unsigned int)u) << 16;
    return __uint_as_float(x);
}
static __device__ __forceinline__ ushort f2bf(float f) {
    union { __hip_bfloat16 b; ushort u; } cv;
    cv.b = __float2bfloat16(f);   // RNE
    return cv.u;
}
static __device__ __forceinline__ float lo2f(unsigned u) {
    return __uint_as_float(u << 16);
}
static __device__ __forceinline__ float hi2f(unsigned u) {
    return __uint_as_float(u & 0xffff0000u);
}
static __device__ __forceinline__ unsigned packbf(float x, float y) {
    return (unsigned)f2bf(x) | ((unsigned)f2bf(y) << 16);
}

// ---- phase A: compact edges into 256 sub-partition queues ----------------

__global__ __launch_bounds__(256)
void compact_edges256(const int* __restrict__ src, const int* __restrict__ dst,
                      int* __restrict__ tail, int2* __restrict__ queue, int E) {
    __shared__ int hist[NQ];
    __shared__ int base[NQ];
    int tid = threadIdx.x;
    int e0 = blockIdx.x * BE;
    int e1 = min(E, e0 + BE);

    hist[tid] = 0;
    __syncthreads();
    for (int e = e0 + tid; e < e1; e += 256)
        atomicAdd(&hist[dst[e] / SUBN], 1);          // LDS atomic
    __syncthreads();
    base[tid] = atomicAdd(&tail[tid], hist[tid]);    // 256 global atomics/blk
    hist[tid] = 0;                                   // reuse as cursor
    __syncthreads();
    for (int e = e0 + tid; e < e1; e += 256) {
        int d = dst[e];
        int s = src[e];
        int p = d / SUBN;
        int pos = base[p] + atomicAdd(&hist[p], 1);  // LDS atomic
        if (pos < QCAP) queue[(size_t)p * QCAP + pos] = make_int2(s, d);
    }
}

// ---- phase B: per-sub-partition exact CSR built entirely in LDS ---------
// Lists padded to multiple of 16 with sentinel N (zero feature row).

__global__ __launch_bounds__(256)
void csr_build_local(const int2* __restrict__ queue, const int* __restrict__ tail,
                     int2* __restrict__ info, int* __restrict__ nbr, int N) {
    __shared__ int lcnt[512];            // >= SUBN
    __shared__ int psum[256];
    __shared__ int lnbr[LCAP];           // 46 KB staging
    int tid = threadIdx.x;
    int p = blockIdx.x;
    int lo = p * SUBN;
    int nt = min(tail[p], QCAP);
    const int2* q = queue + (size_t)p * QCAP;
    int gbase = p * LCAP;

    lcnt[tid] = 0; lcnt[tid + 256] = 0;
    __syncthreads();
    for (int e = tid; e < nt; e += 256)
        atomicAdd(&lcnt[q[e].y - lo], 1);            // LDS atomic
    __syncthreads();

    // exclusive scan over PADDED sizes; thread owns elements 2t, 2t+1
    int d0 = lcnt[2 * tid], d1 = lcnt[2 * tid + 1];
    int p0 = (d0 + 15) & ~15, p1 = (d1 + 15) & ~15;
    int s = p0 + p1;
    psum[tid] = s;
    __syncthreads();
    for (int off = 1; off < 256; off <<= 1) {
        int a = (tid >= off) ? psum[tid - off] : 0;
        __syncthreads();
        psum[tid] += a;
        __syncthreads();
    }
    int st0 = psum[tid] - s;
    int st1 = st0 + p0;
    int ptot = psum[255];

    {
        int li = 2 * tid, n = lo + li;
        if (li < SUBN && n < N) info[n] = make_int2(gbase + st0, d0);
        lcnt[li] = st0;                  // local cursor
        li = 2 * tid + 1; n = lo + li;
        if (li < SUBN && n < N) info[n] = make_int2(gbase + st1, d1);
        lcnt[li] = st1;
    }
    __syncthreads();

    for (int e = tid; e < nt; e += 256) {
        int2 pr = q[e];
        int pos = atomicAdd(&lcnt[pr.y - lo], 1);    // LDS atomic
        lnbr[pos] = pr.x;
    }
    __syncthreads();

    // fill pad slots with sentinel N
    for (int j = st0 + d0; j < st0 + p0; ++j) lnbr[j] = N;
    for (int j = st1 + d1; j < st1 + p1; ++j) lnbr[j] = N;
    __syncthreads();

    for (int i = tid; i < ptot; i += 256)            // coalesced copy-out
        nbr[gbase + i] = lnbr[i];
}

// ---- fp32 -> bf16 convert + pipeline init (tail zero, sentinel rows) ----

__global__ __launch_bounds__(256)
void cvt_bf16_init(const float* __restrict__ in, ushort* __restrict__ xh,
                   ushort* __restrict__ y2l, int* __restrict__ tail,
                   int n4, int N) {
    int i = blockIdx.x * 256 + threadIdx.x;   // one float4 -> ushort4
    if (i < n4) {
        float4 v = *(const float4*)&in[(size_t)i * 4];
        ushort4 u;
        u.x = f2bf(v.x); u.y = f2bf(v.y); u.z = f2bf(v.z); u.w = f2bf(v.w);
        *(ushort4*)&xh[(size_t)i * 4] = u;
    }
    if (blockIdx.x == 0) tail[threadIdx.x] = 0;               // NQ == 256
    if (blockIdx.x == 1) {                                    // zero rows N
        if (threadIdx.x < D1) xh[(size_t)N * D1 + threadIdx.x] = 0;
        if (threadIdx.x < 32) y2l[(size_t)N * 32 + threadIdx.x] = 0;
    }
}

// ---- gather L1: mean of 64-wide bf16 rows. Wave per node. ----------------
// Slots (r,c)=(lane>>3, lane&7): 8 rows per 1KB instruction, unroll x2.

#define ACC8(u) do { \
    a0 += lo2f((u).x); a1 += hi2f((u).x); \
    a2 += lo2f((u).y); a3 += hi2f((u).y); \
    a4 += lo2f((u).z); a5 += hi2f((u).z); \
    a6 += lo2f((u).w); a7 += hi2f((u).w); } while (0)

__global__ __launch_bounds__(256)
void gather_mean8(const ushort* __restrict__ feat,
                  const int2* __restrict__ info,
                  const int* __restrict__ nbr,
                  ushort* __restrict__ mean, int N) {
    int wid  = (blockIdx.x * 256 + threadIdx.x) >> 6;
    int lane = threadIdx.x & 63;
    if (wid >= N) return;
    int2 ii = info[wid];
    int deg = ii.y;
    int m8 = (deg + 7) & ~7;
    const int* nb = nbr + ii.x;
    int r = lane >> 3;          // neighbor slot 0..7
    int c = lane & 7;           // uint4 quad within 64-feature row
    const uint4* f4 = (const uint4*)feat;

    float a0 = 0, a1 = 0, a2 = 0, a3 = 0, a4 = 0, a5 = 0, a6 = 0, a7 = 0;
    int i = 0;
    for (; i + 16 <= m8; i += 16) {
        int e0 = nb[i + r];
        int e1 = nb[i + 8 + r];
        uint4 u0 = f4[(size_t)e0 * 8 + c];
        uint4 u1 = f4[(size_t)e1 * 8 + c];
        ACC8(u0);
        ACC8(u1);
    }
    if (i < m8) {
        int e0 = nb[i + r];
        uint4 u0 = f4[(size_t)e0 * 8 + c];
        ACC8(u0);
    }

    a0 += __shfl_xor(a0, 8, 64); a0 += __shfl_xor(a0, 16, 64); a0 += __shfl_xor(a0, 32, 64);
    a1 += __shfl_xor(a1, 8, 64); a1 += __shfl_xor(a1, 16, 64); a1 += __shfl_xor(a1, 32, 64);
    a2 += __shfl_xor(a2, 8, 64); a2 += __shfl_xor(a2, 16, 64); a2 += __shfl_xor(a2, 32, 64);
    a3 += __shfl_xor(a3, 8, 64); a3 += __shfl_xor(a3, 16, 64); a3 += __shfl_xor(a3, 32, 64);
    a4 += __shfl_xor(a4, 8, 64); a4 += __shfl_xor(a4, 16, 64); a4 += __shfl_xor(a4, 32, 64);
    a5 += __shfl_xor(a5, 8, 64); a5 += __shfl_xor(a5, 16, 64); a5 += __shfl_xor(a5, 32, 64);
    a6 += __shfl_xor(a6, 8, 64); a6 += __shfl_xor(a6, 16, 64); a6 += __shfl_xor(a6, 32, 64);
    a7 += __shfl_xor(a7, 8, 64); a7 += __shfl_xor(a7, 16, 64); a7 += __shfl_xor(a7, 32, 64);

    if (r == 0) {               // lanes 0..7 write the 128B mean row
        float inv = 1.0f / fmaxf((float)deg, 1.0f);
        uint4 o;
        o.x = packbf(a0 * inv, a1 * inv);
        o.y = packbf(a2 * inv, a3 * inv);
        o.z = packbf(a4 * inv, a5 * inv);
        o.w = packbf(a6 * inv, a7 * inv);
        ((uint4*)mean)[(size_t)wid * 8 + c] = o;
    }
}

// ---- gather L2 + output: out[n] = mean(y2l[nbrs]) + y2r[n] + b2 ---------
// Slots (r,c)=(lane>>2, lane&3): 16 rows of 64B per 1KB instruction.

__global__ __launch_bounds__(256)
void gather_out(const ushort* __restrict__ y2l,    // [N+1][32] bf16
                const float* __restrict__ y2r,     // [N][32] fp32
                const float* __restrict__ b2,      // [32]
                const int2* __restrict__ info,
                const int* __restrict__ nbr,
                float* __restrict__ outp, int N) {
    int wid  = (blockIdx.x * 256 + threadIdx.x) >> 6;
    int lane = threadIdx.x & 63;
    if (wid >= N) return;
    int2 ii = info[wid];
    int deg = ii.y;
    int m16 = (deg + 15) & ~15;
    const int* nb = nbr + ii.x;
    int r = lane >> 2;          // neighbor slot 0..15
    int c = lane & 3;           // uint4 quad within 32-feature row
    const uint4* f4 = (const uint4*)y2l;

    float a0 = 0, a1 = 0, a2 = 0, a3 = 0, a4 = 0, a5 = 0, a6 = 0, a7 = 0;
    int i = 0;
    for (; i + 32 <= m16; i += 32) {
        int e0 = nb[i + r];
        int e1 = nb[i + 16 + r];
        uint4 u0 = f4[(size_t)e0 * 4 + c];
        uint4 u1 = f4[(size_t)e1 * 4 + c];
        ACC8(u0);
        ACC8(u1);
    }
    if (i < m16) {
        int e0 = nb[i + r];
        uint4 u0 = f4[(size_t)e0 * 4 + c];
        ACC8(u0);
    }

    // reduce across 16 slots (lane bits 2..5)
    a0 += __shfl_xor(a0, 4, 64); a0 += __shfl_xor(a0, 8, 64); a0 += __shfl_xor(a0, 16, 64); a0 += __shfl_xor(a0, 32, 64);
    a1 += __shfl_xor(a1, 4, 64); a1 += __shfl_xor(a1, 8, 64); a1 += __shfl_xor(a1, 16, 64); a1 += __shfl_xor(a1, 32, 64);
    a2 += __shfl_xor(a2, 4, 64); a2 += __shfl_xor(a2, 8, 64); a2 += __shfl_xor(a2, 16, 64); a2 += __shfl_xor(a2, 32, 64);
    a3 += __shfl_xor(a3, 4, 64); a3 += __shfl_xor(a3, 8, 64); a3 += __shfl_xor(a3, 16, 64); a3 += __shfl_xor(a3, 32, 64);
    a4 += __shfl_xor(a4, 4, 64); a4 += __shfl_xor(a4, 8, 64); a4 += __shfl_xor(a4, 16, 64); a4 += __shfl_xor(a4, 32, 64);
    a5 += __shfl_xor(a5, 4, 64); a5 += __shfl_xor(a5, 8, 64); a5 += __shfl_xor(a5, 16, 64); a5 += __shfl_xor(a5, 32, 64);
    a6 += __shfl_xor(a6, 4, 64); a6 += __shfl_xor(a6, 8, 64); a6 += __shfl_xor(a6, 16, 64); a6 += __shfl_xor(a6, 32, 64);
    a7 += __shfl_xor(a7, 4, 64); a7 += __shfl_xor(a7, 8, 64); a7 += __shfl_xor(a7, 16, 64); a7 += __shfl_xor(a7, 32, 64);

    if (r == 0) {               // lanes 0..3: add y2r + b2, write 32B fp32
        float inv = 1.0f / fmaxf((float)deg, 1.0f);
        size_t o = (size_t)wid * 32 + c * 8;
        float4 r0 = *(const float4*)&y2r[o];
        float4 r1 = *(const float4*)&y2r[o + 4];
        float4 v0, v1;
        v0.x = fmaf(a0, inv, r0.x + b2[c * 8 + 0]);
        v0.y = fmaf(a1, inv, r0.y + b2[c * 8 + 1]);
        v0.z = fmaf(a2, inv, r0.z + b2[c * 8 + 2]);
        v0.w = fmaf(a3, inv, r0.w + b2[c * 8 + 3]);
        v1.x = fmaf(a4, inv, r1.x + b2[c * 8 + 4]);
        v1.y = fmaf(a5, inv, r1.y + b2[c * 8 + 5]);
        v1.z = fmaf(a6, inv, r1.z + b2[c * 8 + 6]);
        v1.w = fmaf(a7, inv, r1.w + b2[c * 8 + 7]);
        *(float4*)&outp[o] = v0;
        *(float4*)&outp[o + 4] = v1;
    }
}

// ---- dense1: h = relu(mean1@W1l + b1 + x@W1r); y2l = h@W2l; y2r = h@W2r --
// Block = 64 nodes; lane = node; wave w owns j-slice [w*16,(w+1)*16).
// h lives only in LDS; the two 32-wide GEMMs share each ds_read (16 FMA/read).

#define TA_STRIDE 66

__global__ __launch_bounds__(256)
void dense_sage1(const ushort* __restrict__ Am,    // mean1 [N][64] bf16
                 const ushort* __restrict__ Ax,    // xh [N][64] bf16
                 const float* __restrict__ Wm,     // W1l [64][64]
                 const float* __restrict__ Wx,     // W1r [64][64]
                 const float* __restrict__ bias,   // b1 [64]
                 const float* __restrict__ W2l,    // [64][32]
                 const float* __restrict__ W2r,    // [64][32]
                 ushort* __restrict__ y2l,         // [N+1][32] bf16
                 float* __restrict__ y2r,          // [N][32] fp32
                 int N) {
    __shared__ char smraw[128 * TA_STRIDE * 2];   // 16.9 KB
    ushort* ta = (ushort*)smraw;
    float*  to = (float*)smraw;                   // h tile [64][65] fp32
    float*  tA = (float*)smraw;                   // y2l tile [32][65]
    float*  tB = ((float*)smraw) + 32 * 65;       // y2r tile [32][65]

    int tid  = threadIdx.x;
    int w    = tid >> 6;
    int lane = tid & 63;
    int n0 = blockIdx.x * 64;

    #pragma unroll
    for (int i = 0; i < 8; ++i) {
        int flat = i * 256 + tid;
        int row  = flat >> 4;
        int c4   = (flat & 15) * 4;
        const ushort* A = (row < 64) ? Am : Ax;
        int node = row & 63;
        int grow = n0 + node;
        ushort4 u = make_ushort4(0, 0, 0, 0);
        if (grow < N) u = *(const ushort4*)&A[(size_t)grow * D1 + c4];
        int kb = ((row < 64) ? 0 : 64) + c4;
        ta[(kb + 0) * TA_STRIDE + node] = u.x;
        ta[(kb + 1) * TA_STRIDE + node] = u.y;
        ta[(kb + 2) * TA_STRIDE + node] = u.z;
        ta[(kb + 3) * TA_STRIDE + node] = u.w;
    }
    __syncthreads();

    int jb = __builtin_amdgcn_readfirstlane(w * 16);
    float c[16];
    #pragma unroll
    for (int j = 0; j < 16; ++j) c[j] = bias[jb + j];

    #pragma unroll 4
    for (int k = 0; k < 64; ++k) {
        float a = bf2f(ta[k * TA_STRIDE + lane]);
        #pragma unroll
        for (int j = 0; j < 16; ++j)
            c[j] = fmaf(a, Wm[k * 64 + jb + j], c[j]);
    }
    #pragma unroll 4
    for (int k = 0; k < 64; ++k) {
        float a = bf2f(ta[(64 + k) * TA_STRIDE + lane]);
        #pragma unroll
        for (int j = 0; j < 16; ++j)
            c[j] = fmaf(a, Wx[k * 64 + jb + j], c[j]);
    }
    #pragma unroll
    for (int j = 0; j < 16; ++j) c[j] = fmaxf(c[j], 0.0f);   // relu

    __syncthreads();   // A-tile consumed -> reuse LDS as fp32 h tile
    #pragma unroll
    for (int j = 0; j < 16; ++j) to[(jb + j) * 65 + lane] = c[j];
    __syncthreads();

    // y2l = h@W2l, y2r = h@W2r; wave w owns jj-slice [w*8,(w+1)*8).
    int jb2 = __builtin_amdgcn_readfirstlane(w * 8);
    float c2[8], c3[8];
    #pragma unroll
    for (int j = 0; j < 8; ++j) { c2[j] = 0.0f; c3[j] = 0.0f; }
    #pragma unroll 4
    for (int k = 0; k < 64; ++k) {
        float a = to[k * 65 + lane];
        #pragma unroll
        for (int j = 0; j < 8; ++j) {
            c2[j] = fmaf(a, W2l[k * 32 + jb2 + j], c2[j]);
            c3[j] = fmaf(a, W2r[k * 32 + jb2 + j], c3[j]);
        }
    }
    __syncthreads();   // h tile consumed -> reuse as y2l/y2r tiles
    #pragma unroll
    for (int j = 0; j < 8; ++j) {
        tA[(jb2 + j) * 65 + lane] = c2[j];
        tB[(jb2 + j) * 65 + lane] = c3[j];
    }
    __syncthreads();

    // y2l store (bf16, ushort4 chunks): 64 nodes x 8 quads
    #pragma unroll
    for (int i = 0; i < 2; ++i) {
        int flat = i * 256 + tid;
        int node = flat >> 3;
        int q    = flat & 7;
        int grow = n0 + node;
        if (grow < N) {
            ushort4 u;
            u.x = f2bf(tA[(q * 4 + 0) * 65 + node]);
            u.y = f2bf(tA[(q * 4 + 1) * 65 + node]);
            u.z = f2bf(tA[(q * 4 + 2) * 65 + node]);
            u.w = f2bf(tA[(q * 4 + 3) * 65 + node]);
            *(ushort4*)&y2l[(size_t)grow * 32 + q * 4] = u;
        }
    }
    // y2r store (fp32, float4 chunks): 64 nodes x 8 quads
    #pragma unroll
    for (int i = 0; i < 2; ++i) {
        int flat = i * 256 + tid;
        int node = flat >> 3;
        int q    = flat & 7;
        int grow = n0 + node;
        if (grow < N) {
            float4 v;
            v.x = tB[(q * 4 + 0) * 65 + node];
            v.y = tB[(q * 4 + 1) * 65 + node];
            v.z = tB[(q * 4 + 2) * 65 + node];
            v.w = tB[(q * 4 + 3) * 65 + node];
            *(float4*)&y2r[(size_t)grow * 32 + q * 4] = v;
        }
    }
}

// ---- launch -------------------------------------------------------------

extern "C" void kernel_launch(void* const* d_in, const int* in_sizes, int n_in,
                              void* d_out, int out_size, void* d_ws, size_t ws_size,
                              hipStream_t stream) {
    const float* x   = (const float*)d_in[0];
    const int*   ei  = (const int*)d_in[1];
    const float* W1l = (const float*)d_in[2];
    const float* W1r = (const float*)d_in[3];
    const float* b1  = (const float*)d_in[4];
    const float* W2l = (const float*)d_in[5];
    const float* W2r = (const float*)d_in[6];
    const float* b2  = (const float*)d_in[7];
    float* out = (float*)d_out;

    int N = in_sizes[0] / D1;
    int E = in_sizes[1] / 2;
    const int* src = ei;
    const int* dst = ei + E;

    char* ws = (char*)d_ws;
    auto alignup = [](size_t v) { return (v + 255) & ~(size_t)255; };
    size_t off = 0;
    int*    tail  = (int*)(ws + off);    off += alignup(NQ * 4);
    int2*   queue = (int2*)(ws + off);   off += alignup((size_t)NQ * QCAP * 8);
    int*    nbr   = (int*)(ws + off);    off += alignup((size_t)NQ * LCAP * 4);
    int2*   info  = (int2*)(ws + off);   off += alignup((size_t)N * 8);
    ushort* xh    = (ushort*)(ws + off); off += alignup((size_t)(N + 1) * D1 * 2);
    ushort* y2l   = (ushort*)(ws + off); off += alignup((size_t)(N + 1) * 32 * 2);
    float*  y2r   = (float*)(ws + off);  off += alignup((size_t)N * 32 * 4);
    // layer-1 mean lives in d_out: written by gather1, read by dense1,
    // then d_out is fully overwritten by gather_out with the final output.
    ushort* mean1 = (ushort*)d_out;      // N*64*2B = 12.8MB == out_size bytes

    int gb = (N + 3) / 4;         // gather: wave per node, 4 waves/block
    int db = (N + 63) / 64;       // dense: 64 nodes/block
    int cb = ((N * D1 / 4) + 255) / 256;
    int ab = (E + BE - 1) / BE;   // phase-A blocks (235)

    cvt_bf16_init<<<cb, 256, 0, stream>>>(x, xh, y2l, tail, N * D1 / 4, N);
    compact_edges256<<<ab, 256, 0, stream>>>(src, dst, tail, queue, E);
    csr_build_local<<<NQ, 256, 0, stream>>>(queue, tail, info, nbr, N);

    gather_mean8<<<gb, 256, 0, stream>>>(xh, info, nbr, mean1, N);
    dense_sage1<<<db, 256, 0, stream>>>(mean1, xh, W1l, W1r, b1, W2l, W2r, y2l, y2r, N);
    gather_out<<<gb, 256, 0, stream>>>(y2l, y2r, b2, info, nbr, out, N);
}

// Round 17
// 149.640 us; speedup vs baseline: 1.0470x; 1.0470x over previous
//
#include <hip/hip_runtime.h>
#include <hip/hip_bf16.h>

// GraphSAGE 2-layer, N=100000, E=1200000, D: 64 -> 64 -> 32, fp32 in/out.
// R17: dense1 LDS-depressurize. R16 profile: dense1 = 52-58us, VALU 33%,
// HBM 7% -> stalled on 192 per-thread LDS reads (128 ds_read_u16 A-tile +
// 64 ds_read_b32 h-tile). Fix: pack 2 bf16 per uint along k -> 96 b32
// reads (each feeds 32 FMAs), staged/stored as b32 pairs. h rounds to bf16
// before y2 (same numeric path as R14, absmax 0.03125).
// Rest identical to R16: full layer-2 push-through (y2l=h@W2l gathered,
// y2r=h@W2r per-node, out fused into gather2), atomic-free 256-queue
// build, pad-16 CSR, bf16 activations.

#define D1 64
#define NQ 256               // sub-partition queues (== blockDim for compact)
#define SUBN 391             // ceil(N/256); d/SUBN <= 255 for d < 100096
#define QCAP 5632            // per-queue cap; avg 4687, sigma ~68 (13+ sigma)
#define LCAP 11520           // staging cap >= QCAP + SUBN*15 = 11497
#define BE 5120              // edges per phase-A block (2 streaming passes)

static __device__ __forceinline__ float bf2f(ushort u) {
    unsigned int x = ((unsigned int)u) << 16;
    return __uint_as_float(x);
}
static __device__ __forceinline__ ushort f2bf(float f) {
    union { __hip_bfloat16 b; ushort u; } cv;
    cv.b = __float2bfloat16(f);   // RNE
    return cv.u;
}
static __device__ __forceinline__ float lo2f(unsigned u) {
    return __uint_as_float(u << 16);
}
static __device__ __forceinline__ float hi2f(unsigned u) {
    return __uint_as_float(u & 0xffff0000u);
}
static __device__ __forceinline__ unsigned packbf(float x, float y) {
    return (unsigned)f2bf(x) | ((unsigned)f2bf(y) << 16);
}

// ---- phase A: compact edges into 256 sub-partition queues ----------------

__global__ __launch_bounds__(256)
void compact_edges256(const int* __restrict__ src, const int* __restrict__ dst,
                      int* __restrict__ tail, int2* __restrict__ queue, int E) {
    __shared__ int hist[NQ];
    __shared__ int base[NQ];
    int tid = threadIdx.x;
    int e0 = blockIdx.x * BE;
    int e1 = min(E, e0 + BE);

    hist[tid] = 0;
    __syncthreads();
    for (int e = e0 + tid; e < e1; e += 256)
        atomicAdd(&hist[dst[e] / SUBN], 1);          // LDS atomic
    __syncthreads();
    base[tid] = atomicAdd(&tail[tid], hist[tid]);    // 256 global atomics/blk
    hist[tid] = 0;                                   // reuse as cursor
    __syncthreads();
    for (int e = e0 + tid; e < e1; e += 256) {
        int d = dst[e];
        int s = src[e];
        int p = d / SUBN;
        int pos = base[p] + atomicAdd(&hist[p], 1);  // LDS atomic
        if (pos < QCAP) queue[(size_t)p * QCAP + pos] = make_int2(s, d);
    }
}

// ---- phase B: per-sub-partition exact CSR built entirely in LDS ---------
// Lists padded to multiple of 16 with sentinel N (zero feature row).

__global__ __launch_bounds__(256)
void csr_build_local(const int2* __restrict__ queue, const int* __restrict__ tail,
                     int2* __restrict__ info, int* __restrict__ nbr, int N) {
    __shared__ int lcnt[512];            // >= SUBN
    __shared__ int psum[256];
    __shared__ int lnbr[LCAP];           // 46 KB staging
    int tid = threadIdx.x;
    int p = blockIdx.x;
    int lo = p * SUBN;
    int nt = min(tail[p], QCAP);
    const int2* q = queue + (size_t)p * QCAP;
    int gbase = p * LCAP;

    lcnt[tid] = 0; lcnt[tid + 256] = 0;
    __syncthreads();
    for (int e = tid; e < nt; e += 256)
        atomicAdd(&lcnt[q[e].y - lo], 1);            // LDS atomic
    __syncthreads();

    // exclusive scan over PADDED sizes; thread owns elements 2t, 2t+1
    int d0 = lcnt[2 * tid], d1 = lcnt[2 * tid + 1];
    int p0 = (d0 + 15) & ~15, p1 = (d1 + 15) & ~15;
    int s = p0 + p1;
    psum[tid] = s;
    __syncthreads();
    for (int off = 1; off < 256; off <<= 1) {
        int a = (tid >= off) ? psum[tid - off] : 0;
        __syncthreads();
        psum[tid] += a;
        __syncthreads();
    }
    int st0 = psum[tid] - s;
    int st1 = st0 + p0;
    int ptot = psum[255];

    {
        int li = 2 * tid, n = lo + li;
        if (li < SUBN && n < N) info[n] = make_int2(gbase + st0, d0);
        lcnt[li] = st0;                  // local cursor
        li = 2 * tid + 1; n = lo + li;
        if (li < SUBN && n < N) info[n] = make_int2(gbase + st1, d1);
        lcnt[li] = st1;
    }
    __syncthreads();

    for (int e = tid; e < nt; e += 256) {
        int2 pr = q[e];
        int pos = atomicAdd(&lcnt[pr.y - lo], 1);    // LDS atomic
        lnbr[pos] = pr.x;
    }
    __syncthreads();

    // fill pad slots with sentinel N
    for (int j = st0 + d0; j < st0 + p0; ++j) lnbr[j] = N;
    for (int j = st1 + d1; j < st1 + p1; ++j) lnbr[j] = N;
    __syncthreads();

    for (int i = tid; i < ptot; i += 256)            // coalesced copy-out
        nbr[gbase + i] = lnbr[i];
}

// ---- fp32 -> bf16 convert + pipeline init (tail zero, sentinel rows) ----

__global__ __launch_bounds__(256)
void cvt_bf16_init(const float* __restrict__ in, ushort* __restrict__ xh,
                   ushort* __restrict__ y2l, int* __restrict__ tail,
                   int n4, int N) {
    int i = blockIdx.x * 256 + threadIdx.x;   // one float4 -> ushort4
    if (i < n4) {
        float4 v = *(const float4*)&in[(size_t)i * 4];
        ushort4 u;
        u.x = f2bf(v.x); u.y = f2bf(v.y); u.z = f2bf(v.z); u.w = f2bf(v.w);
        *(ushort4*)&xh[(size_t)i * 4] = u;
    }
    if (blockIdx.x == 0) tail[threadIdx.x] = 0;               // NQ == 256
    if (blockIdx.x == 1) {                                    // zero rows N
        if (threadIdx.x < D1) xh[(size_t)N * D1 + threadIdx.x] = 0;
        if (threadIdx.x < 32) y2l[(size_t)N * 32 + threadIdx.x] = 0;
    }
}

// ---- gather L1: mean of 64-wide bf16 rows. Wave per node. ----------------

#define ACC8(u) do { \
    a0 += lo2f((u).x); a1 += hi2f((u).x); \
    a2 += lo2f((u).y); a3 += hi2f((u).y); \
    a4 += lo2f((u).z); a5 += hi2f((u).z); \
    a6 += lo2f((u).w); a7 += hi2f((u).w); } while (0)

__global__ __launch_bounds__(256)
void gather_mean8(const ushort* __restrict__ feat,
                  const int2* __restrict__ info,
                  const int* __restrict__ nbr,
                  ushort* __restrict__ mean, int N) {
    int wid  = (blockIdx.x * 256 + threadIdx.x) >> 6;
    int lane = threadIdx.x & 63;
    if (wid >= N) return;
    int2 ii = info[wid];
    int deg = ii.y;
    int m8 = (deg + 7) & ~7;
    const int* nb = nbr + ii.x;
    int r = lane >> 3;          // neighbor slot 0..7
    int c = lane & 7;           // uint4 quad within 64-feature row
    const uint4* f4 = (const uint4*)feat;

    float a0 = 0, a1 = 0, a2 = 0, a3 = 0, a4 = 0, a5 = 0, a6 = 0, a7 = 0;
    int i = 0;
    for (; i + 16 <= m8; i += 16) {
        int e0 = nb[i + r];
        int e1 = nb[i + 8 + r];
        uint4 u0 = f4[(size_t)e0 * 8 + c];
        uint4 u1 = f4[(size_t)e1 * 8 + c];
        ACC8(u0);
        ACC8(u1);
    }
    if (i < m8) {
        int e0 = nb[i + r];
        uint4 u0 = f4[(size_t)e0 * 8 + c];
        ACC8(u0);
    }

    a0 += __shfl_xor(a0, 8, 64); a0 += __shfl_xor(a0, 16, 64); a0 += __shfl_xor(a0, 32, 64);
    a1 += __shfl_xor(a1, 8, 64); a1 += __shfl_xor(a1, 16, 64); a1 += __shfl_xor(a1, 32, 64);
    a2 += __shfl_xor(a2, 8, 64); a2 += __shfl_xor(a2, 16, 64); a2 += __shfl_xor(a2, 32, 64);
    a3 += __shfl_xor(a3, 8, 64); a3 += __shfl_xor(a3, 16, 64); a3 += __shfl_xor(a3, 32, 64);
    a4 += __shfl_xor(a4, 8, 64); a4 += __shfl_xor(a4, 16, 64); a4 += __shfl_xor(a4, 32, 64);
    a5 += __shfl_xor(a5, 8, 64); a5 += __shfl_xor(a5, 16, 64); a5 += __shfl_xor(a5, 32, 64);
    a6 += __shfl_xor(a6, 8, 64); a6 += __shfl_xor(a6, 16, 64); a6 += __shfl_xor(a6, 32, 64);
    a7 += __shfl_xor(a7, 8, 64); a7 += __shfl_xor(a7, 16, 64); a7 += __shfl_xor(a7, 32, 64);

    if (r == 0) {               // lanes 0..7 write the 128B mean row
        float inv = 1.0f / fmaxf((float)deg, 1.0f);
        uint4 o;
        o.x = packbf(a0 * inv, a1 * inv);
        o.y = packbf(a2 * inv, a3 * inv);
        o.z = packbf(a4 * inv, a5 * inv);
        o.w = packbf(a6 * inv, a7 * inv);
        ((uint4*)mean)[(size_t)wid * 8 + c] = o;
    }
}

// ---- gather L2 + output: out[n] = mean(y2l[nbrs]) + y2r[n] + b2 ---------

__global__ __launch_bounds__(256)
void gather_out(const ushort* __restrict__ y2l,    // [N+1][32] bf16
                const float* __restrict__ y2r,     // [N][32] fp32
                const float* __restrict__ b2,      // [32]
                const int2* __restrict__ info,
                const int* __restrict__ nbr,
                float* __restrict__ outp, int N) {
    int wid  = (blockIdx.x * 256 + threadIdx.x) >> 6;
    int lane = threadIdx.x & 63;
    if (wid >= N) return;
    int2 ii = info[wid];
    int deg = ii.y;
    int m16 = (deg + 15) & ~15;
    const int* nb = nbr + ii.x;
    int r = lane >> 2;          // neighbor slot 0..15
    int c = lane & 3;           // uint4 quad within 32-feature row
    const uint4* f4 = (const uint4*)y2l;

    float a0 = 0, a1 = 0, a2 = 0, a3 = 0, a4 = 0, a5 = 0, a6 = 0, a7 = 0;
    int i = 0;
    for (; i + 32 <= m16; i += 32) {
        int e0 = nb[i + r];
        int e1 = nb[i + 16 + r];
        uint4 u0 = f4[(size_t)e0 * 4 + c];
        uint4 u1 = f4[(size_t)e1 * 4 + c];
        ACC8(u0);
        ACC8(u1);
    }
    if (i < m16) {
        int e0 = nb[i + r];
        uint4 u0 = f4[(size_t)e0 * 4 + c];
        ACC8(u0);
    }

    a0 += __shfl_xor(a0, 4, 64); a0 += __shfl_xor(a0, 8, 64); a0 += __shfl_xor(a0, 16, 64); a0 += __shfl_xor(a0, 32, 64);
    a1 += __shfl_xor(a1, 4, 64); a1 += __shfl_xor(a1, 8, 64); a1 += __shfl_xor(a1, 16, 64); a1 += __shfl_xor(a1, 32, 64);
    a2 += __shfl_xor(a2, 4, 64); a2 += __shfl_xor(a2, 8, 64); a2 += __shfl_xor(a2, 16, 64); a2 += __shfl_xor(a2, 32, 64);
    a3 += __shfl_xor(a3, 4, 64); a3 += __shfl_xor(a3, 8, 64); a3 += __shfl_xor(a3, 16, 64); a3 += __shfl_xor(a3, 32, 64);
    a4 += __shfl_xor(a4, 4, 64); a4 += __shfl_xor(a4, 8, 64); a4 += __shfl_xor(a4, 16, 64); a4 += __shfl_xor(a4, 32, 64);
    a5 += __shfl_xor(a5, 4, 64); a5 += __shfl_xor(a5, 8, 64); a5 += __shfl_xor(a5, 16, 64); a5 += __shfl_xor(a5, 32, 64);
    a6 += __shfl_xor(a6, 4, 64); a6 += __shfl_xor(a6, 8, 64); a6 += __shfl_xor(a6, 16, 64); a6 += __shfl_xor(a6, 32, 64);
    a7 += __shfl_xor(a7, 4, 64); a7 += __shfl_xor(a7, 8, 64); a7 += __shfl_xor(a7, 16, 64); a7 += __shfl_xor(a7, 32, 64);

    if (r == 0) {               // lanes 0..3: add y2r + b2, write 32B fp32
        float inv = 1.0f / fmaxf((float)deg, 1.0f);
        size_t o = (size_t)wid * 32 + c * 8;
        float4 r0 = *(const float4*)&y2r[o];
        float4 r1 = *(const float4*)&y2r[o + 4];
        float4 v0, v1;
        v0.x = fmaf(a0, inv, r0.x + b2[c * 8 + 0]);
        v0.y = fmaf(a1, inv, r0.y + b2[c * 8 + 1]);
        v0.z = fmaf(a2, inv, r0.z + b2[c * 8 + 2]);
        v0.w = fmaf(a3, inv, r0.w + b2[c * 8 + 3]);
        v1.x = fmaf(a4, inv, r1.x + b2[c * 8 + 4]);
        v1.y = fmaf(a5, inv, r1.y + b2[c * 8 + 5]);
        v1.z = fmaf(a6, inv, r1.z + b2[c * 8 + 6]);
        v1.w = fmaf(a7, inv, r1.w + b2[c * 8 + 7]);
        *(float4*)&outp[o] = v0;
        *(float4*)&outp[o + 4] = v1;
    }
}

// ---- dense1: h = relu(mean1@W1l + b1 + x@W1r); y2l = h@W2l; y2r = h@W2r --
// Block = 64 nodes; lane = node; wave w owns j-slice [w*16,(w+1)*16).
// LDS packed as 2xbf16 per uint along k: A-tile [64 packed rows][65],
// h-tile [32 packed rows][65]. 96 b32 reads/thread (was 192 reads).

__global__ __launch_bounds__(256)
void dense_sage1(const ushort* __restrict__ Am,    // mean1 [N][64] bf16
                 const ushort* __restrict__ Ax,    // xh [N][64] bf16
                 const float* __restrict__ Wm,     // W1l [64][64]
                 const float* __restrict__ Wx,     // W1r [64][64]
                 const float* __restrict__ bias,   // b1 [64]
                 const float* __restrict__ W2l,    // [64][32]
                 const float* __restrict__ W2r,    // [64][32]
                 ushort* __restrict__ y2l,         // [N+1][32] bf16
                 float* __restrict__ y2r,          // [N][32] fp32
                 int N) {
    __shared__ char smraw[64 * 65 * 4];           // 16.6 KB, multi-purpose
    unsigned* ta2 = (unsigned*)smraw;             // A: [64 packed k][65]
    unsigned* th2 = (unsigned*)smraw;             // h: [32 packed j][65]
    float*    tA  = (float*)smraw;                // y2l: [32][65]
    float*    tB  = ((float*)smraw) + 32 * 65;    // y2r: [32][65]

    int tid  = threadIdx.x;
    int w    = tid >> 6;
    int lane = tid & 63;
    int n0 = blockIdx.x * 64;

    // stage 128 logical A-rows (64 mean + 64 x) x 64 k, transposed+packed:
    // ta2[kk][node], kk = (isX ? 32 : 0) + k/2.
    #pragma unroll
    for (int i = 0; i < 8; ++i) {
        int flat = i * 256 + tid;        // 0..2047 ushort4-chunks
        int row  = flat >> 4;            // 0..127 (node within half)
        int c4   = (flat & 15) * 4;      // k offset 0..60
        const ushort* A = (row < 64) ? Am : Ax;
        int node = row & 63;
        int grow = n0 + node;
        ushort4 u = make_ushort4(0, 0, 0, 0);
        if (grow < N) u = *(const ushort4*)&A[(size_t)grow * D1 + c4];
        int kb = ((row < 64) ? 0 : 32) + (c4 >> 1);
        ta2[(kb + 0) * 65 + node] = (unsigned)u.x | ((unsigned)u.y << 16);
        ta2[(kb + 1) * 65 + node] = (unsigned)u.z | ((unsigned)u.w << 16);
    }
    __syncthreads();

    int jb = __builtin_amdgcn_readfirstlane(w * 16);
    float c[16];
    #pragma unroll
    for (int j = 0; j < 16; ++j) c[j] = bias[jb + j];

    #pragma unroll 4
    for (int kk = 0; kk < 32; ++kk) {            // mean half: k = 2kk, 2kk+1
        unsigned pa = ta2[kk * 65 + lane];
        float a0 = lo2f(pa), a1 = hi2f(pa);
        #pragma unroll
        for (int j = 0; j < 16; ++j) {
            c[j] = fmaf(a0, Wm[(2 * kk) * 64 + jb + j], c[j]);
            c[j] = fmaf(a1, Wm[(2 * kk + 1) * 64 + jb + j], c[j]);
        }
    }
    #pragma unroll 4
    for (int kk = 0; kk < 32; ++kk) {            // x half
        unsigned pa = ta2[(32 + kk) * 65 + lane];
        float a0 = lo2f(pa), a1 = hi2f(pa);
        #pragma unroll
        for (int j = 0; j < 16; ++j) {
            c[j] = fmaf(a0, Wx[(2 * kk) * 64 + jb + j], c[j]);
            c[j] = fmaf(a1, Wx[(2 * kk + 1) * 64 + jb + j], c[j]);
        }
    }
    #pragma unroll
    for (int j = 0; j < 16; ++j) c[j] = fmaxf(c[j], 0.0f);   // relu

    __syncthreads();   // A-tile consumed -> reuse LDS as packed bf16 h tile
    #pragma unroll
    for (int j2 = 0; j2 < 8; ++j2)
        th2[((jb >> 1) + j2) * 65 + lane] = packbf(c[2 * j2], c[2 * j2 + 1]);
    __syncthreads();

    // y2l = h@W2l, y2r = h@W2r; wave w owns jj-slice [w*8,(w+1)*8).
    int jb2 = __builtin_amdgcn_readfirstlane(w * 8);
    float c2[8], c3[8];
    #pragma unroll
    for (int j = 0; j < 8; ++j) { c2[j] = 0.0f; c3[j] = 0.0f; }
    #pragma unroll 4
    for (int kk = 0; kk < 32; ++kk) {            // h: k = 2kk, 2kk+1
        unsigned pa = th2[kk * 65 + lane];
        float a0 = lo2f(pa), a1 = hi2f(pa);
        #pragma unroll
        for (int j = 0; j < 8; ++j) {
            c2[j] = fmaf(a0, W2l[(2 * kk) * 32 + jb2 + j], c2[j]);
            c2[j] = fmaf(a1, W2l[(2 * kk + 1) * 32 + jb2 + j], c2[j]);
            c3[j] = fmaf(a0, W2r[(2 * kk) * 32 + jb2 + j], c3[j]);
            c3[j] = fmaf(a1, W2r[(2 * kk + 1) * 32 + jb2 + j], c3[j]);
        }
    }
    __syncthreads();   // h tile consumed -> reuse as y2l/y2r fp32 tiles
    #pragma unroll
    for (int j = 0; j < 8; ++j) {
        tA[(jb2 + j) * 65 + lane] = c2[j];
        tB[(jb2 + j) * 65 + lane] = c3[j];
    }
    __syncthreads();

    // y2l store (bf16, ushort4 chunks): 64 nodes x 8 quads
    #pragma unroll
    for (int i = 0; i < 2; ++i) {
        int flat = i * 256 + tid;
        int node = flat >> 3;
        int q    = flat & 7;
        int grow = n0 + node;
        if (grow < N) {
            ushort4 u;
            u.x = f2bf(tA[(q * 4 + 0) * 65 + node]);
            u.y = f2bf(tA[(q * 4 + 1) * 65 + node]);
            u.z = f2bf(tA[(q * 4 + 2) * 65 + node]);
            u.w = f2bf(tA[(q * 4 + 3) * 65 + node]);
            *(ushort4*)&y2l[(size_t)grow * 32 + q * 4] = u;
        }
    }
    // y2r store (fp32, float4 chunks): 64 nodes x 8 quads
    #pragma unroll
    for (int i = 0; i < 2; ++i) {
        int flat = i * 256 + tid;
        int node = flat >> 3;
        int q    = flat & 7;
        int grow = n0 + node;
        if (grow < N) {
            float4 v;
            v.x = tB[(q * 4 + 0) * 65 + node];
            v.y = tB[(q * 4 + 1) * 65 + node];
            v.z = tB[(q * 4 + 2) * 65 + node];
            v.w = tB[(q * 4 + 3) * 65 + node];
            *(float4*)&y2r[(size_t)grow * 32 + q * 4] = v;
        }
    }
}

// ---- launch -------------------------------------------------------------

extern "C" void kernel_launch(void* const* d_in, const int* in_sizes, int n_in,
                              void* d_out, int out_size, void* d_ws, size_t ws_size,
                              hipStream_t stream) {
    const float* x   = (const float*)d_in[0];
    const int*   ei  = (const int*)d_in[1];
    const float* W1l = (const float*)d_in[2];
    const float* W1r = (const float*)d_in[3];
    const float* b1  = (const float*)d_in[4];
    const float* W2l = (const float*)d_in[5];
    const float* W2r = (const float*)d_in[6];
    const float* b2  = (const float*)d_in[7];
    float* out = (float*)d_out;

    int N = in_sizes[0] / D1;
    int E = in_sizes[1] / 2;
    const int* src = ei;
    const int* dst = ei + E;

    char* ws = (char*)d_ws;
    auto alignup = [](size_t v) { return (v + 255) & ~(size_t)255; };
    size_t off = 0;
    int*    tail  = (int*)(ws + off);    off += alignup(NQ * 4);
    int2*   queue = (int2*)(ws + off);   off += alignup((size_t)NQ * QCAP * 8);
    int*    nbr   = (int*)(ws + off);    off += alignup((size_t)NQ * LCAP * 4);
    int2*   info  = (int2*)(ws + off);   off += alignup((size_t)N * 8);
    ushort* xh    = (ushort*)(ws + off); off += alignup((size_t)(N + 1) * D1 * 2);
    ushort* y2l   = (ushort*)(ws + off); off += alignup((size_t)(N + 1) * 32 * 2);
    float*  y2r   = (float*)(ws + off);  off += alignup((size_t)N * 32 * 4);
    // layer-1 mean lives in d_out: written by gather1, read by dense1,
    // then d_out is fully overwritten by gather_out with the final output.
    ushort* mean1 = (ushort*)d_out;      // N*64*2B = 12.8MB == out_size bytes

    int gb = (N + 3) / 4;         // gather: wave per node, 4 waves/block
    int db = (N + 63) / 64;       // dense: 64 nodes/block
    int cb = ((N * D1 / 4) + 255) / 256;
    int ab = (E + BE - 1) / BE;   // phase-A blocks (235)

    cvt_bf16_init<<<cb, 256, 0, stream>>>(x, xh, y2l, tail, N * D1 / 4, N);
    compact_edges256<<<ab, 256, 0, stream>>>(src, dst, tail, queue, E);
    csr_build_local<<<NQ, 256, 0, stream>>>(queue, tail, info, nbr, N);

    gather_mean8<<<gb, 256, 0, stream>>>(xh, info, nbr, mean1, N);
    dense_sage1<<<db, 256, 0, stream>>>(mean1, xh, W1l, W1r, b1, W2l, W2r, y2l, y2r, N);
    gather_out<<<gb, 256, 0, stream>>>(y2l, y2r, b2, info, nbr, out, N);
}

// Round 18
// 142.276 us; speedup vs baseline: 1.1012x; 1.0518x over previous
//
#include <hip/hip_runtime.h>
#include <hip/hip_bf16.h>

// GraphSAGE 2-layer, N=100000, E=1200000, D: 64 -> 64 -> 32, fp32 in/out.
// R18: dense1 on MFMA. R17 showed dense1 at its VALU floor (42us, 3072
// FMA/thread). Rewrite: v_mfma_f32_16x16x32_bf16, per-block [64x128]@
// [128x64] (layer1) + [64x64]@[64x64] (y2l|y2r), 24 MFMAs/wave. A-frags
// straight from global (8 contiguous bf16, row=lane&15, k=(lane>>4)*8);
// B-frags from pre-transposed bf16 weights WB1[j][k]/WB2[j2][k] (24KB,
// L1-resident; built in cvt_init). h transposed D->A layout via per-wave
// 16x72 LDS tile (2-way banks, same-wave, no barrier). Weights now bf16
// (absmax budget: 0.031 -> ~0.05, threshold 0.098).
// Rest = R17: push-through layer 2, atomic-free 256-queue build, pad-16
// CSR, bf16 activations, fused gather_out.

#define D1 64
#define NQ 256
#define SUBN 391
#define QCAP 5632
#define LCAP 11520
#define BE 5120

typedef __attribute__((ext_vector_type(8))) short bf16x8;
typedef __attribute__((ext_vector_type(4))) float f32x4;

static __device__ __forceinline__ float bf2f(ushort u) {
    unsigned int x = ((unsigned int)u) << 16;
    return __uint_as_float(x);
}
static __device__ __forceinline__ ushort f2bf(float f) {
    union { __hip_bfloat16 b; ushort u; } cv;
    cv.b = __float2bfloat16(f);   // RNE
    return cv.u;
}
static __device__ __forceinline__ float lo2f(unsigned u) {
    return __uint_as_float(u << 16);
}
static __device__ __forceinline__ float hi2f(unsigned u) {
    return __uint_as_float(u & 0xffff0000u);
}
static __device__ __forceinline__ unsigned packbf(float x, float y) {
    return (unsigned)f2bf(x) | ((unsigned)f2bf(y) << 16);
}

// ---- phase A: compact edges into 256 sub-partition queues ----------------

__global__ __launch_bounds__(256)
void compact_edges256(const int* __restrict__ src, const int* __restrict__ dst,
                      int* __restrict__ tail, int2* __restrict__ queue, int E) {
    __shared__ int hist[NQ];
    __shared__ int base[NQ];
    int tid = threadIdx.x;
    int e0 = blockIdx.x * BE;
    int e1 = min(E, e0 + BE);

    hist[tid] = 0;
    __syncthreads();
    for (int e = e0 + tid; e < e1; e += 256)
        atomicAdd(&hist[dst[e] / SUBN], 1);          // LDS atomic
    __syncthreads();
    base[tid] = atomicAdd(&tail[tid], hist[tid]);    // 256 global atomics/blk
    hist[tid] = 0;                                   // reuse as cursor
    __syncthreads();
    for (int e = e0 + tid; e < e1; e += 256) {
        int d = dst[e];
        int s = src[e];
        int p = d / SUBN;
        int pos = base[p] + atomicAdd(&hist[p], 1);  // LDS atomic
        if (pos < QCAP) queue[(size_t)p * QCAP + pos] = make_int2(s, d);
    }
}

// ---- phase B: per-sub-partition exact CSR built entirely in LDS ---------

__global__ __launch_bounds__(256)
void csr_build_local(const int2* __restrict__ queue, const int* __restrict__ tail,
                     int2* __restrict__ info, int* __restrict__ nbr, int N) {
    __shared__ int lcnt[512];
    __shared__ int psum[256];
    __shared__ int lnbr[LCAP];
    int tid = threadIdx.x;
    int p = blockIdx.x;
    int lo = p * SUBN;
    int nt = min(tail[p], QCAP);
    const int2* q = queue + (size_t)p * QCAP;
    int gbase = p * LCAP;

    lcnt[tid] = 0; lcnt[tid + 256] = 0;
    __syncthreads();
    for (int e = tid; e < nt; e += 256)
        atomicAdd(&lcnt[q[e].y - lo], 1);
    __syncthreads();

    int d0 = lcnt[2 * tid], d1 = lcnt[2 * tid + 1];
    int p0 = (d0 + 15) & ~15, p1 = (d1 + 15) & ~15;
    int s = p0 + p1;
    psum[tid] = s;
    __syncthreads();
    for (int off = 1; off < 256; off <<= 1) {
        int a = (tid >= off) ? psum[tid - off] : 0;
        __syncthreads();
        psum[tid] += a;
        __syncthreads();
    }
    int st0 = psum[tid] - s;
    int st1 = st0 + p0;
    int ptot = psum[255];

    {
        int li = 2 * tid, n = lo + li;
        if (li < SUBN && n < N) info[n] = make_int2(gbase + st0, d0);
        lcnt[li] = st0;
        li = 2 * tid + 1; n = lo + li;
        if (li < SUBN && n < N) info[n] = make_int2(gbase + st1, d1);
        lcnt[li] = st1;
    }
    __syncthreads();

    for (int e = tid; e < nt; e += 256) {
        int2 pr = q[e];
        int pos = atomicAdd(&lcnt[pr.y - lo], 1);
        lnbr[pos] = pr.x;
    }
    __syncthreads();

    for (int j = st0 + d0; j < st0 + p0; ++j) lnbr[j] = N;
    for (int j = st1 + d1; j < st1 + p1; ++j) lnbr[j] = N;
    __syncthreads();

    for (int i = tid; i < ptot; i += 256)
        nbr[gbase + i] = lnbr[i];
}

// ---- fp32->bf16 convert + init + weight transpose to [j][k] bf16 --------

__global__ __launch_bounds__(256)
void cvt_bf16_init(const float* __restrict__ in, ushort* __restrict__ xh,
                   ushort* __restrict__ y2l, int* __restrict__ tail,
                   const float* __restrict__ W1l, const float* __restrict__ W1r,
                   const float* __restrict__ W2l, const float* __restrict__ W2r,
                   ushort* __restrict__ WB1, ushort* __restrict__ WB2,
                   int n4, int N) {
    int i = blockIdx.x * 256 + threadIdx.x;
    if (i < n4) {
        float4 v = *(const float4*)&in[(size_t)i * 4];
        ushort4 u;
        u.x = f2bf(v.x); u.y = f2bf(v.y); u.z = f2bf(v.z); u.w = f2bf(v.w);
        *(ushort4*)&xh[(size_t)i * 4] = u;
    }
    if (blockIdx.x == 0) tail[threadIdx.x] = 0;
    if (blockIdx.x == 1) {                          // zero sentinel rows
        if (threadIdx.x < D1) xh[(size_t)N * D1 + threadIdx.x] = 0;
        if (threadIdx.x < 32) y2l[(size_t)N * 32 + threadIdx.x] = 0;
    }
    if (blockIdx.x == 2) {                          // WB1[j][k], k<64: W1l
        for (int idx = threadIdx.x; idx < 64 * 128; idx += 256) {
            int j = idx >> 7, k = idx & 127;
            float v = (k < 64) ? W1l[k * 64 + j] : W1r[(k - 64) * 64 + j];
            WB1[idx] = f2bf(v);
        }
    }
    if (blockIdx.x == 3) {                          // WB2[j2][k]
        for (int idx = threadIdx.x; idx < 64 * 64; idx += 256) {
            int j2 = idx >> 6, k = idx & 63;
            float v = (j2 < 32) ? W2l[k * 32 + j2] : W2r[k * 32 + (j2 - 32)];
            WB2[idx] = f2bf(v);
        }
    }
}

// ---- gather L1: mean of 64-wide bf16 rows. Wave per node. ----------------

#define ACC8(u) do { \
    a0 += lo2f((u).x); a1 += hi2f((u).x); \
    a2 += lo2f((u).y); a3 += hi2f((u).y); \
    a4 += lo2f((u).z); a5 += hi2f((u).z); \
    a6 += lo2f((u).w); a7 += hi2f((u).w); } while (0)

__global__ __launch_bounds__(256)
void gather_mean8(const ushort* __restrict__ feat,
                  const int2* __restrict__ info,
                  const int* __restrict__ nbr,
                  ushort* __restrict__ mean, int N) {
    int wid  = (blockIdx.x * 256 + threadIdx.x) >> 6;
    int lane = threadIdx.x & 63;
    if (wid >= N) return;
    int2 ii = info[wid];
    int deg = ii.y;
    int m8 = (deg + 7) & ~7;
    const int* nb = nbr + ii.x;
    int r = lane >> 3;
    int c = lane & 7;
    const uint4* f4 = (const uint4*)feat;

    float a0 = 0, a1 = 0, a2 = 0, a3 = 0, a4 = 0, a5 = 0, a6 = 0, a7 = 0;
    int i = 0;
    for (; i + 16 <= m8; i += 16) {
        int e0 = nb[i + r];
        int e1 = nb[i + 8 + r];
        uint4 u0 = f4[(size_t)e0 * 8 + c];
        uint4 u1 = f4[(size_t)e1 * 8 + c];
        ACC8(u0);
        ACC8(u1);
    }
    if (i < m8) {
        int e0 = nb[i + r];
        uint4 u0 = f4[(size_t)e0 * 8 + c];
        ACC8(u0);
    }

    a0 += __shfl_xor(a0, 8, 64); a0 += __shfl_xor(a0, 16, 64); a0 += __shfl_xor(a0, 32, 64);
    a1 += __shfl_xor(a1, 8, 64); a1 += __shfl_xor(a1, 16, 64); a1 += __shfl_xor(a1, 32, 64);
    a2 += __shfl_xor(a2, 8, 64); a2 += __shfl_xor(a2, 16, 64); a2 += __shfl_xor(a2, 32, 64);
    a3 += __shfl_xor(a3, 8, 64); a3 += __shfl_xor(a3, 16, 64); a3 += __shfl_xor(a3, 32, 64);
    a4 += __shfl_xor(a4, 8, 64); a4 += __shfl_xor(a4, 16, 64); a4 += __shfl_xor(a4, 32, 64);
    a5 += __shfl_xor(a5, 8, 64); a5 += __shfl_xor(a5, 16, 64); a5 += __shfl_xor(a5, 32, 64);
    a6 += __shfl_xor(a6, 8, 64); a6 += __shfl_xor(a6, 16, 64); a6 += __shfl_xor(a6, 32, 64);
    a7 += __shfl_xor(a7, 8, 64); a7 += __shfl_xor(a7, 16, 64); a7 += __shfl_xor(a7, 32, 64);

    if (r == 0) {
        float inv = 1.0f / fmaxf((float)deg, 1.0f);
        uint4 o;
        o.x = packbf(a0 * inv, a1 * inv);
        o.y = packbf(a2 * inv, a3 * inv);
        o.z = packbf(a4 * inv, a5 * inv);
        o.w = packbf(a6 * inv, a7 * inv);
        ((uint4*)mean)[(size_t)wid * 8 + c] = o;
    }
}

// ---- gather L2 + output: out[n] = mean(y2l[nbrs]) + y2r[n] + b2 ---------

__global__ __launch_bounds__(256)
void gather_out(const ushort* __restrict__ y2l,
                const float* __restrict__ y2r,
                const float* __restrict__ b2,
                const int2* __restrict__ info,
                const int* __restrict__ nbr,
                float* __restrict__ outp, int N) {
    int wid  = (blockIdx.x * 256 + threadIdx.x) >> 6;
    int lane = threadIdx.x & 63;
    if (wid >= N) return;
    int2 ii = info[wid];
    int deg = ii.y;
    int m16 = (deg + 15) & ~15;
    const int* nb = nbr + ii.x;
    int r = lane >> 2;
    int c = lane & 3;
    const uint4* f4 = (const uint4*)y2l;

    float a0 = 0, a1 = 0, a2 = 0, a3 = 0, a4 = 0, a5 = 0, a6 = 0, a7 = 0;
    int i = 0;
    for (; i + 32 <= m16; i += 32) {
        int e0 = nb[i + r];
        int e1 = nb[i + 16 + r];
        uint4 u0 = f4[(size_t)e0 * 4 + c];
        uint4 u1 = f4[(size_t)e1 * 4 + c];
        ACC8(u0);
        ACC8(u1);
    }
    if (i < m16) {
        int e0 = nb[i + r];
        uint4 u0 = f4[(size_t)e0 * 4 + c];
        ACC8(u0);
    }

    a0 += __shfl_xor(a0, 4, 64); a0 += __shfl_xor(a0, 8, 64); a0 += __shfl_xor(a0, 16, 64); a0 += __shfl_xor(a0, 32, 64);
    a1 += __shfl_xor(a1, 4, 64); a1 += __shfl_xor(a1, 8, 64); a1 += __shfl_xor(a1, 16, 64); a1 += __shfl_xor(a1, 32, 64);
    a2 += __shfl_xor(a2, 4, 64); a2 += __shfl_xor(a2, 8, 64); a2 += __shfl_xor(a2, 16, 64); a2 += __shfl_xor(a2, 32, 64);
    a3 += __shfl_xor(a3, 4, 64); a3 += __shfl_xor(a3, 8, 64); a3 += __shfl_xor(a3, 16, 64); a3 += __shfl_xor(a3, 32, 64);
    a4 += __shfl_xor(a4, 4, 64); a4 += __shfl_xor(a4, 8, 64); a4 += __shfl_xor(a4, 16, 64); a4 += __shfl_xor(a4, 32, 64);
    a5 += __shfl_xor(a5, 4, 64); a5 += __shfl_xor(a5, 8, 64); a5 += __shfl_xor(a5, 16, 64); a5 += __shfl_xor(a5, 32, 64);
    a6 += __shfl_xor(a6, 4, 64); a6 += __shfl_xor(a6, 8, 64); a6 += __shfl_xor(a6, 16, 64); a6 += __shfl_xor(a6, 32, 64);
    a7 += __shfl_xor(a7, 4, 64); a7 += __shfl_xor(a7, 8, 64); a7 += __shfl_xor(a7, 16, 64); a7 += __shfl_xor(a7, 32, 64);

    if (r == 0) {
        float inv = 1.0f / fmaxf((float)deg, 1.0f);
        size_t o = (size_t)wid * 32 + c * 8;
        float4 r0 = *(const float4*)&y2r[o];
        float4 r1 = *(const float4*)&y2r[o + 4];
        float4 v0, v1;
        v0.x = fmaf(a0, inv, r0.x + b2[c * 8 + 0]);
        v0.y = fmaf(a1, inv, r0.y + b2[c * 8 + 1]);
        v0.z = fmaf(a2, inv, r0.z + b2[c * 8 + 2]);
        v0.w = fmaf(a3, inv, r0.w + b2[c * 8 + 3]);
        v1.x = fmaf(a4, inv, r1.x + b2[c * 8 + 4]);
        v1.y = fmaf(a5, inv, r1.y + b2[c * 8 + 5]);
        v1.z = fmaf(a6, inv, r1.z + b2[c * 8 + 6]);
        v1.w = fmaf(a7, inv, r1.w + b2[c * 8 + 7]);
        *(float4*)&outp[o] = v0;
        *(float4*)&outp[o + 4] = v1;
    }
}

// ---- dense (MFMA): h = relu([mean|x]@W1 + b1); y2l=h@W2l; y2r=h@W2r -----
// Block = 64 nodes = 4 waves x 16-node strips. A-frag: row=lane&15,
// k=(lane>>4)*8 (8 contiguous bf16 from global). B-frag: same shape from
// WB[j][k]. D: col(j)=lane&15, row(node)=(lane>>4)*4+reg. h goes through a
// per-wave [16][72] LDS tile (D-layout write -> A-layout read, same wave).

__global__ __launch_bounds__(256)
void dense_mfma(const ushort* __restrict__ Am,     // mean1 [N][64] bf16
                const ushort* __restrict__ Ax,     // xh [N+1][64] bf16
                const ushort* __restrict__ WB1,    // [64 j][128 k] bf16
                const ushort* __restrict__ WB2,    // [64 j2][64 k] bf16
                const float* __restrict__ b1,      // [64]
                ushort* __restrict__ y2l,          // [N+1][32] bf16
                float* __restrict__ y2r,           // [N][32] fp32
                int N) {
    __shared__ ushort hl[4][16 * 72];   // per-wave h tile, stride 72 (144B)
    int tid  = threadIdx.x;
    int w    = tid >> 6;
    int lane = tid & 63;
    int mrow = lane & 15;               // fragment row (node or j)
    int kg   = lane >> 4;               // k-group
    int nbase = blockIdx.x * 64 + w * 16;
    int arow = min(nbase + mrow, N - 1);

    // A fragments: K-steps 0,1 from mean, 2,3 from x
    bf16x8 a[4];
    a[0] = *(const bf16x8*)&Am[(size_t)arow * 64 +      kg * 8];
    a[1] = *(const bf16x8*)&Am[(size_t)arow * 64 + 32 + kg * 8];
    a[2] = *(const bf16x8*)&Ax[(size_t)arow * 64 +      kg * 8];
    a[3] = *(const bf16x8*)&Ax[(size_t)arow * 64 + 32 + kg * 8];

    f32x4 acc[4];
    #pragma unroll
    for (int t = 0; t < 4; ++t) acc[t] = (f32x4){0.f, 0.f, 0.f, 0.f};

    #pragma unroll
    for (int s = 0; s < 4; ++s) {
        #pragma unroll
        for (int t = 0; t < 4; ++t) {
            bf16x8 b = *(const bf16x8*)&WB1[(size_t)(t * 16 + mrow) * 128 + s * 32 + kg * 8];
            acc[t] = __builtin_amdgcn_mfma_f32_16x16x32_bf16(a[s], b, acc[t], 0, 0, 0);
        }
    }

    // bias + relu; write h into per-wave LDS tile (node = kg*4+reg, j = t*16+mrow)
    #pragma unroll
    for (int t = 0; t < 4; ++t) {
        float bv = b1[t * 16 + mrow];
        #pragma unroll
        for (int r = 0; r < 4; ++r) {
            float hv = fmaxf(acc[t][r] + bv, 0.0f);
            hl[w][(kg * 4 + r) * 72 + t * 16 + mrow] = f2bf(hv);
        }
    }
    // same-wave write->read: DS ops in order, no barrier needed

    bf16x8 a2[2];
    a2[0] = *(const bf16x8*)&hl[w][mrow * 72 +      kg * 8];
    a2[1] = *(const bf16x8*)&hl[w][mrow * 72 + 32 + kg * 8];

    f32x4 acc2[4];
    #pragma unroll
    for (int t = 0; t < 4; ++t) acc2[t] = (f32x4){0.f, 0.f, 0.f, 0.f};

    #pragma unroll
    for (int s = 0; s < 2; ++s) {
        #pragma unroll
        for (int t = 0; t < 4; ++t) {
            bf16x8 b = *(const bf16x8*)&WB2[(size_t)(t * 16 + mrow) * 64 + s * 32 + kg * 8];
            acc2[t] = __builtin_amdgcn_mfma_f32_16x16x32_bf16(a2[s], b, acc2[t], 0, 0, 0);
        }
    }

    // stores: t=0,1 -> y2l (bf16); t=2,3 -> y2r (fp32)
    #pragma unroll
    for (int t = 0; t < 2; ++t) {
        #pragma unroll
        for (int r = 0; r < 4; ++r) {
            int grow = nbase + kg * 4 + r;
            if (grow < N)
                y2l[(size_t)grow * 32 + t * 16 + mrow] = f2bf(acc2[t][r]);
        }
    }
    #pragma unroll
    for (int t = 2; t < 4; ++t) {
        #pragma unroll
        for (int r = 0; r < 4; ++r) {
            int grow = nbase + kg * 4 + r;
            if (grow < N)
                y2r[(size_t)grow * 32 + (t - 2) * 16 + mrow] = acc2[t][r];
        }
    }
}

// ---- launch -------------------------------------------------------------

extern "C" void kernel_launch(void* const* d_in, const int* in_sizes, int n_in,
                              void* d_out, int out_size, void* d_ws, size_t ws_size,
                              hipStream_t stream) {
    const float* x   = (const float*)d_in[0];
    const int*   ei  = (const int*)d_in[1];
    const float* W1l = (const float*)d_in[2];
    const float* W1r = (const float*)d_in[3];
    const float* b1  = (const float*)d_in[4];
    const float* W2l = (const float*)d_in[5];
    const float* W2r = (const float*)d_in[6];
    const float* b2  = (const float*)d_in[7];
    float* out = (float*)d_out;

    int N = in_sizes[0] / D1;
    int E = in_sizes[1] / 2;
    const int* src = ei;
    const int* dst = ei + E;

    char* ws = (char*)d_ws;
    auto alignup = [](size_t v) { return (v + 255) & ~(size_t)255; };
    size_t off = 0;
    int*    tail  = (int*)(ws + off);    off += alignup(NQ * 4);
    int2*   queue = (int2*)(ws + off);   off += alignup((size_t)NQ * QCAP * 8);
    int*    nbr   = (int*)(ws + off);    off += alignup((size_t)NQ * LCAP * 4);
    int2*   info  = (int2*)(ws + off);   off += alignup((size_t)N * 8);
    ushort* xh    = (ushort*)(ws + off); off += alignup((size_t)(N + 1) * D1 * 2);
    ushort* y2l   = (ushort*)(ws + off); off += alignup((size_t)(N + 1) * 32 * 2);
    float*  y2r   = (float*)(ws + off);  off += alignup((size_t)N * 32 * 4);
    ushort* WB1   = (ushort*)(ws + off); off += alignup(64 * 128 * 2);
    ushort* WB2   = (ushort*)(ws + off); off += alignup(64 * 64 * 2);
    // layer-1 mean lives in d_out: written by gather1, read by dense_mfma,
    // then d_out is fully overwritten by gather_out with the final output.
    ushort* mean1 = (ushort*)d_out;      // N*64*2B = 12.8MB == out_size bytes

    int gb = (N + 3) / 4;
    int db = (N + 63) / 64;
    int cb = ((N * D1 / 4) + 255) / 256;
    int ab = (E + BE - 1) / BE;

    cvt_bf16_init<<<cb, 256, 0, stream>>>(x, xh, y2l, tail,
                                          W1l, W1r, W2l, W2r, WB1, WB2,
                                          N * D1 / 4, N);
    compact_edges256<<<ab, 256, 0, stream>>>(src, dst, tail, queue, E);
    csr_build_local<<<NQ, 256, 0, stream>>>(queue, tail, info, nbr, N);

    gather_mean8<<<gb, 256, 0, stream>>>(xh, info, nbr, mean1, N);
    dense_mfma<<<db, 256, 0, stream>>>(mean1, xh, WB1, WB2, b1, y2l, y2r, N);
    gather_out<<<gb, 256, 0, stream>>>(y2l, y2r, b2, info, nbr, out, N);
}